// Round 4
// baseline (2116.029 us; speedup 1.0000x reference)
//
#include <hip/hip_runtime.h>
#include <cstdint>
#include <cstddef>

// ---------------------------------------------------------------------------
// EdgeDecoder, swapped-operand formulation, s=1 (spill-proof under 128 VGPR).
//   Layer0: D0 = W0^T (A-frag, LDS) @ X^T (B-frag, gathered)   [C: lane=edge col]
//   transform: ELU + f16 pack + permlane32/16_swap -> layer-1 B-frags (no LDS)
//   Layer1: D1 = W1^T (A-frag, LDS) @ H0^T (B-frag, registers)
//   Layer2: per-lane dot (32 ch) + xor16/xor32 reduce + store (16 lanes)
// History: rounds 2-3 proved this toolchain pins the budget at 128 VGPR
// regardless of __launch_bounds__ arg2 (1 or 2) -> ~50-reg spill -> ~3 GB
// scratch traffic -> 1225 us. Fix: one edge-set per tile (16 edges), peak
// live ~95 VGPR: a[8](32) + acc0[8](32) + weight temps + misc. All fragment
// math identical to the verified round-2 kernel, s dimension dropped.
// ---------------------------------------------------------------------------

#define E_EDGES       1000000
#define NTILES        62500      // E / 16
#define GRID_BLKS     512        // 256 blocks per decoder, interleaved
#define WAVES_PER_DEC 2048       // 256 blocks * 8 waves

typedef _Float16 half8  __attribute__((ext_vector_type(8)));
typedef _Float16 half4v __attribute__((ext_vector_type(4)));
typedef _Float16 half2v __attribute__((ext_vector_type(2)));
typedef float    f32x4  __attribute__((ext_vector_type(4)));
typedef unsigned int uint4v __attribute__((ext_vector_type(4)));

__device__ __forceinline__ float elu_f(float x) {
    return (x > 0.f) ? x : (__expf(x) - 1.f);
}

// Cross-lane word redistribution for C-layout -> B-fragment conversion.
//   lo[l] = (l<32 ? A0 : A1)[ ((l>>4)&1)*32 +      (l&15) ]
//   hi[l] = (l<32 ? A0 : A1)[ ((l>>4)&1)*32 + 16 + (l&15) ]
// Realized as permlane32_swap + permlane16_swap (both outputs used).
// Verified correct in rounds 1-3 (passed, absmax 0.0039).
__device__ __forceinline__ void xpose_pair(unsigned int A0, unsigned int A1,
                                           unsigned int& lo, unsigned int& hi) {
#if __has_builtin(__builtin_amdgcn_permlane32_swap) && __has_builtin(__builtin_amdgcn_permlane16_swap)
    auto t = __builtin_amdgcn_permlane32_swap(A0, A1, false, false);
    auto u = __builtin_amdgcn_permlane16_swap(t[0], t[1], false, false);
    lo = u[0]; hi = u[1];
#else
    const int l = (int)(threadIdx.x & 63);
    const int src = (((l >> 4) & 1) << 5) | (l & 15);
    unsigned int x0 = (unsigned int)__shfl((int)A0, src);
    unsigned int x1 = (unsigned int)__shfl((int)A1, src);
    unsigned int y0 = (unsigned int)__shfl((int)A0, src + 16);
    unsigned int y1 = (unsigned int)__shfl((int)A1, src + 16);
    lo = (l < 32) ? x0 : x1;
    hi = (l < 32) ? y0 : y1;
#endif
}

// fused f32 -> f16 conversion of both embedding tables
__global__ void cvt_tables(const float* __restrict__ u, const float* __restrict__ it,
                           _Float16* __restrict__ ou, _Float16* __restrict__ oi,
                           int n4u, int n4i) {
    int i = blockIdx.x * blockDim.x + threadIdx.x;
    const float4* src; half4v* dst; int j;
    if (i < n4u) { src = (const float4*)u; dst = (half4v*)ou; j = i; }
    else {
        j = i - n4u;
        if (j >= n4i) return;
        src = (const float4*)it; dst = (half4v*)oi;
    }
    float4 f = src[j];
    half4v h;
    h[0] = (_Float16)f.x; h[1] = (_Float16)f.y;
    h[2] = (_Float16)f.z; h[3] = (_Float16)f.w;
    dst[j] = h;
}

struct SMem {
    _Float16 wf[49152];                 // 96 KiB: W0 frags (64) + W1 frags (32)
    float b0f[128], b1f[128], w2f[128]; // 1.5 KiB epilogue constants
};

template<bool PRE16>
__global__ __attribute__((amdgpu_waves_per_eu(1, 2))) __launch_bounds__(512)
void edge_mlp(
    const void* __restrict__ tabU, const void* __restrict__ tabI,
    const int* __restrict__ ui_src, const int* __restrict__ ui_dst,
    const int* __restrict__ iu_src, const int* __restrict__ iu_dst,
    const float* __restrict__ W0_ui, const float* __restrict__ b0_ui,
    const float* __restrict__ W1_ui, const float* __restrict__ b1_ui,
    const float* __restrict__ W2_ui, const float* __restrict__ b2_ui,
    const float* __restrict__ W0_iu, const float* __restrict__ b0_iu,
    const float* __restrict__ W1_iu, const float* __restrict__ b1_iu,
    const float* __restrict__ W2_iu, const float* __restrict__ b2_iu,
    float* __restrict__ out)
{
    __shared__ __align__(16) SMem sm;

    const int dec = blockIdx.x & 1;
    const void* src_tab = dec ? tabI : tabU;
    const void* dst_tab = dec ? tabU : tabI;
    const int* src_idx = dec ? iu_src : ui_src;
    const int* dst_idx = dec ? iu_dst : ui_dst;
    const float* W0 = dec ? W0_iu : W0_ui;
    const float* b0 = dec ? b0_iu : b0_ui;
    const float* W1 = dec ? W1_iu : W1_ui;
    const float* b1 = dec ? b1_iu : b1_ui;
    const float* W2 = dec ? W2_iu : W2_ui;
    const float* b2 = dec ? b2_iu : b2_ui;
    float* op = out + (dec ? E_EDGES : 0);

    const int tid = threadIdx.x;
    const int l = tid & 63;        // lane
    const int w = tid >> 6;        // wave 0..7
    const int n = l & 15;
    const int g = l >> 4;          // lane quad 0..3

    // ---- preload W0^T A-frags: frag f = kk*8 + hr, 64 frags, 8 waves x 8 ----
    // frag elem (lane l, i): W0[(kk*32 + g*8 + i)*128 + hr*16 + n]
    #pragma unroll
    for (int q = 0; q < 8; ++q) {
        const int f = w * 8 + q;
        const int kk = f >> 3, hr = f & 7;
        const int kbase = kk * 32 + g * 8;
        const int col = hr * 16 + n;
        half8 fr;
        #pragma unroll
        for (int i = 0; i < 8; ++i) fr[i] = (_Float16)W0[(kbase + i) * 128 + col];
        *(half8*)&sm.wf[f * 512 + l * 8] = fr;
    }
    // ---- preload W1^T A-frags: 32 frags, 8 waves x 4 ----
    #pragma unroll
    for (int q = 0; q < 4; ++q) {
        const int f = w * 4 + q;
        const int kk = f >> 3, hr = f & 7;
        const int kbase = kk * 32 + g * 8;
        const int col = hr * 16 + n;
        half8 fr;
        #pragma unroll
        for (int i = 0; i < 8; ++i) fr[i] = (_Float16)W1[(kbase + i) * 128 + col];
        *(half8*)&sm.wf[32768 + f * 512 + l * 8] = fr;
    }
    // ---- epilogue constants ----
    if (tid < 128) {
        sm.b0f[tid] = b0[tid];
        sm.b1f[tid] = b1[tid];
        sm.w2f[tid] = W2[tid];
    }
    const float b2s = b2[0];
    __syncthreads();   // only barrier; main loop is barrier-free

    const half8* w0f = (const half8*)&sm.wf[0];
    const half8* w1f = (const half8*)&sm.wf[32768];

    const int wid = (blockIdx.x >> 1) * 8 + w;     // 0..2047 within decoder

    for (int t = wid; t < NTILES; t += WAVES_PER_DEC) {
        const int e0 = t * 16;

        // ---- gather X^T B-frag: 16 edges, K=256 (src||dst), B col = lane n ----
        const int e = e0 + n;
        const int si = src_idx[e];
        const int di = dst_idx[e];
        half8 a[8];
        if constexpr (PRE16) {
            const half8* rs = (const half8*)((const _Float16*)src_tab + (size_t)si * 128) + g;
            const half8* rd = (const half8*)((const _Float16*)dst_tab + (size_t)di * 128) + g;
            #pragma unroll
            for (int kk = 0; kk < 4; ++kk) a[kk]     = rs[kk * 4];
            #pragma unroll
            for (int kk = 0; kk < 4; ++kk) a[4 + kk] = rd[kk * 4];
        } else {
            const float* rs = (const float*)src_tab + (size_t)si * 128 + g * 8;
            const float* rd = (const float*)dst_tab + (size_t)di * 128 + g * 8;
            #pragma unroll
            for (int kk = 0; kk < 8; ++kk) {
                const float* base = (kk < 4) ? (rs + kk * 32) : (rd + (kk - 4) * 32);
                float4 p0 = *(const float4*)base;
                float4 p1 = *(const float4*)(base + 4);
                half8 fr;
                fr[0] = (_Float16)p0.x; fr[1] = (_Float16)p0.y;
                fr[2] = (_Float16)p0.z; fr[3] = (_Float16)p0.w;
                fr[4] = (_Float16)p1.x; fr[5] = (_Float16)p1.y;
                fr[6] = (_Float16)p1.z; fr[7] = (_Float16)p1.w;
                a[kk] = fr;
            }
        }

        // ---- layer 0: acc0[hr] = W0^T @ X^T ----
        f32x4 acc0[8];
        #pragma unroll
        for (int hr = 0; hr < 8; ++hr) acc0[hr] = (f32x4){0.f, 0.f, 0.f, 0.f};
        #pragma unroll
        for (int kk = 0; kk < 8; ++kk) {
            #pragma unroll
            for (int hr = 0; hr < 8; ++hr) {
                const half8 wf = w0f[(kk * 8 + hr) * 64 + l];
                acc0[hr] = __builtin_amdgcn_mfma_f32_16x16x32_f16(wf, a[kk], acc0[hr], 0, 0, 0);
            }
        }

        // ---- bias+ELU + pack + permlane: C-layout -> layer-1 B-frags ----
        unsigned int v01[8], v23[8];
        #pragma unroll
        for (int hr = 0; hr < 8; ++hr) {
            const f32x4 b0r = *(const f32x4*)&sm.b0f[hr * 16 + g * 4];
            half2v p01, p23;
            p01[0] = (_Float16)elu_f(acc0[hr][0] + b0r[0]);
            p01[1] = (_Float16)elu_f(acc0[hr][1] + b0r[1]);
            p23[0] = (_Float16)elu_f(acc0[hr][2] + b0r[2]);
            p23[1] = (_Float16)elu_f(acc0[hr][3] + b0r[3]);
            v01[hr] = __builtin_bit_cast(unsigned int, p01);
            v23[hr] = __builtin_bit_cast(unsigned int, p23);
        }
        half8 bfr[4];
        #pragma unroll
        for (int kk = 0; kk < 4; ++kk) {
            unsigned int w0lo, w0hi, w1lo, w1hi;
            xpose_pair(v01[2 * kk], v01[2 * kk + 1], w0lo, w0hi);
            xpose_pair(v23[2 * kk], v23[2 * kk + 1], w1lo, w1hi);
            uint4v wd;
            wd.x = w0lo;   // elems i0,i1 (v=0,1 from groups {0,2})
            wd.y = w1lo;   // elems i2,i3 (v=2,3 from groups {0,2})
            wd.z = w0hi;   // elems i4,i5 (v=0,1 from groups {1,3})
            wd.w = w1hi;   // elems i6,i7 (v=2,3 from groups {1,3})
            bfr[kk] = __builtin_bit_cast(half8, wd);
        }

        // ---- layer 1: acc1[hr] = W1^T @ H0^T ----
        f32x4 acc1[8];
        #pragma unroll
        for (int hr = 0; hr < 8; ++hr) acc1[hr] = (f32x4){0.f, 0.f, 0.f, 0.f};
        #pragma unroll
        for (int kk = 0; kk < 4; ++kk) {
            #pragma unroll
            for (int hr = 0; hr < 8; ++hr) {
                const half8 wf = w1f[(kk * 8 + hr) * 64 + l];
                acc1[hr] = __builtin_amdgcn_mfma_f32_16x16x32_f16(wf, bfr[kk], acc1[hr], 0, 0, 0);
            }
        }

        // ---- layer 2: per-lane 32-ch dot, reduce across lane quads ----
        float accs = 0.f;
        #pragma unroll
        for (int hr = 0; hr < 8; ++hr) {
            const f32x4 b1r = *(const f32x4*)&sm.b1f[hr * 16 + g * 4];
            const f32x4 w2r = *(const f32x4*)&sm.w2f[hr * 16 + g * 4];
            #pragma unroll
            for (int v = 0; v < 4; ++v)
                accs += elu_f(acc1[hr][v] + b1r[v]) * w2r[v];
        }
        accs += __shfl_xor(accs, 16);
        accs += __shfl_xor(accs, 32);
        // lanes 0..15 hold edge e0+n
        if (l < 16) {
            op[e0 + l] = 1.f / (1.f + __expf(-(accs + b2s)));
        }
    }
}

extern "C" void kernel_launch(void* const* d_in, const int* in_sizes, int n_in,
                              void* d_out, int out_size, void* d_ws, size_t ws_size,
                              hipStream_t stream) {
    const float* user_emb = (const float*)d_in[0];
    const float* item_emb = (const float*)d_in[1];
    const int* ui_src = (const int*)d_in[2];
    const int* ui_dst = (const int*)d_in[3];
    const int* iu_src = (const int*)d_in[4];
    const int* iu_dst = (const int*)d_in[5];
    const float* W0_ui = (const float*)d_in[6];
    const float* b0_ui = (const float*)d_in[7];
    const float* W1_ui = (const float*)d_in[8];
    const float* b1_ui = (const float*)d_in[9];
    const float* W2_ui = (const float*)d_in[10];
    const float* b2_ui = (const float*)d_in[11];
    const float* W0_iu = (const float*)d_in[12];
    const float* b0_iu = (const float*)d_in[13];
    const float* W1_iu = (const float*)d_in[14];
    const float* b1_iu = (const float*)d_in[15];
    const float* W2_iu = (const float*)d_in[16];
    const float* b2_iu = (const float*)d_in[17];
    float* out = (float*)d_out;

    const size_t nuser = (size_t)100000 * 128;
    const size_t nitem = (size_t)50000 * 128;
    const size_t need = (nuser + nitem) * sizeof(unsigned short);

    if (ws_size >= need) {
        _Float16* u16 = (_Float16*)d_ws;
        _Float16* i16 = u16 + nuser;
        const int n4u = (int)(nuser / 4);
        const int n4i = (int)(nitem / 4);
        cvt_tables<<<dim3((unsigned)((n4u + n4i + 255) / 256)), dim3(256), 0, stream>>>(
            user_emb, item_emb, u16, i16, n4u, n4i);
        edge_mlp<true><<<dim3(GRID_BLKS), dim3(512), 0, stream>>>(
            (const void*)u16, (const void*)i16,
            ui_src, ui_dst, iu_src, iu_dst,
            W0_ui, b0_ui, W1_ui, b1_ui, W2_ui, b2_ui,
            W0_iu, b0_iu, W1_iu, b1_iu, W2_iu, b2_iu, out);
    } else {
        edge_mlp<false><<<dim3(GRID_BLKS), dim3(512), 0, stream>>>(
            (const void*)user_emb, (const void*)item_emb,
            ui_src, ui_dst, iu_src, iu_dst,
            W0_ui, b0_ui, W1_ui, b1_ui, W2_ui, b2_ui,
            W0_iu, b0_iu, W1_iu, b1_iu, W2_iu, b2_iu, out);
    }
}

// Round 5
// 422.738 us; speedup vs baseline: 5.0055x; 5.0055x over previous
//
#include <hip/hip_runtime.h>
#include <cstdint>
#include <cstddef>

// ---------------------------------------------------------------------------
// EdgeDecoder, swapped-operand formulation, AGPR-pinned accumulators.
//   Layer0: D0 = W0^T (A-frag, LDS) @ X^T (B-frag, gathered)   [C: lane=edge col]
//   transform: ELU + f16 pack + permlane32/16_swap -> layer-1 B-frags (no LDS)
//   Layer1: D1 = W1^T (A-frag, LDS) @ H0^T (B-frag, registers)
//   Layer2: per-lane dot (32 ch) + xor16/xor32 reduce + coalesced store
// History: rounds 2-4 all spilled at a 128 arch-VGPR cap (FETCH 3.5-5 GB of
// scratch traffic) because intrinsic MFMA kept accumulators in VGPRs. Round-0
// (88 VGPR, no spill, 128+ live values) worked because its accumulators were
// in AGPRs. Fix: inline-asm MFMA with "+a" constraint pins accs to AGPRs,
// freeing ~128 arch VGPRs. s=2 working set then fits: consts 24 + a[2][8] 64
// + temps ~35 ~= 125 arch VGPRs + <=128 AGPRs (<=256 total, 2 waves/SIMD).
// ---------------------------------------------------------------------------

#define E_EDGES       1000000
#define NTILES        31250      // E / 32
#define GRID_BLKS     512        // 256 blocks per decoder, interleaved
#define WAVES_PER_DEC 2048       // 256 blocks * 8 waves

typedef _Float16 half8  __attribute__((ext_vector_type(8)));
typedef _Float16 half4v __attribute__((ext_vector_type(4)));
typedef _Float16 half2v __attribute__((ext_vector_type(2)));
typedef float    f32x4  __attribute__((ext_vector_type(4)));
typedef unsigned int uint4v __attribute__((ext_vector_type(4)));

__device__ __forceinline__ float elu_f(float x) {
    return (x > 0.f) ? x : (__expf(x) - 1.f);
}

// MFMA with accumulator pinned to AGPRs ("a" register class). D=A*B+C, C==D.
// srcA = weight fragment, srcB = activation fragment (swapped-operand form).
__device__ __forceinline__ void mfma_a(f32x4& acc, half8 af, half8 bf) {
    asm("v_mfma_f32_16x16x32_f16 %0, %1, %2, %0"
        : "+a"(acc)
        : "v"(af), "v"(bf));
}

// Cross-lane word redistribution for C-layout -> B-fragment conversion.
//   lo[l] = (l<32 ? A0 : A1)[ ((l>>4)&1)*32 +      (l&15) ]
//   hi[l] = (l<32 ? A0 : A1)[ ((l>>4)&1)*32 + 16 + (l&15) ]
// Realized as permlane32_swap + permlane16_swap (both outputs used).
// Verified correct in rounds 1-4 (passed, absmax 0.0039).
__device__ __forceinline__ void xpose_pair(unsigned int A0, unsigned int A1,
                                           unsigned int& lo, unsigned int& hi) {
#if __has_builtin(__builtin_amdgcn_permlane32_swap) && __has_builtin(__builtin_amdgcn_permlane16_swap)
    auto t = __builtin_amdgcn_permlane32_swap(A0, A1, false, false);
    auto u = __builtin_amdgcn_permlane16_swap(t[0], t[1], false, false);
    lo = u[0]; hi = u[1];
#else
    const int l = (int)(threadIdx.x & 63);
    const int src = (((l >> 4) & 1) << 5) | (l & 15);
    unsigned int x0 = (unsigned int)__shfl((int)A0, src);
    unsigned int x1 = (unsigned int)__shfl((int)A1, src);
    unsigned int y0 = (unsigned int)__shfl((int)A0, src + 16);
    unsigned int y1 = (unsigned int)__shfl((int)A1, src + 16);
    lo = (l < 32) ? x0 : x1;
    hi = (l < 32) ? y0 : y1;
#endif
}

// fused f32 -> f16 conversion of both embedding tables
__global__ void cvt_tables(const float* __restrict__ u, const float* __restrict__ it,
                           _Float16* __restrict__ ou, _Float16* __restrict__ oi,
                           int n4u, int n4i) {
    int i = blockIdx.x * blockDim.x + threadIdx.x;
    const float4* src; half4v* dst; int j;
    if (i < n4u) { src = (const float4*)u; dst = (half4v*)ou; j = i; }
    else {
        j = i - n4u;
        if (j >= n4i) return;
        src = (const float4*)it; dst = (half4v*)oi;
    }
    float4 f = src[j];
    half4v h;
    h[0] = (_Float16)f.x; h[1] = (_Float16)f.y;
    h[2] = (_Float16)f.z; h[3] = (_Float16)f.w;
    dst[j] = h;
}

template<bool PRE16>
__global__ __launch_bounds__(512, 2) void edge_mlp(
    const void* __restrict__ tabU, const void* __restrict__ tabI,
    const int* __restrict__ ui_src, const int* __restrict__ ui_dst,
    const int* __restrict__ iu_src, const int* __restrict__ iu_dst,
    const float* __restrict__ W0_ui, const float* __restrict__ b0_ui,
    const float* __restrict__ W1_ui, const float* __restrict__ b1_ui,
    const float* __restrict__ W2_ui, const float* __restrict__ b2_ui,
    const float* __restrict__ W0_iu, const float* __restrict__ b0_iu,
    const float* __restrict__ W1_iu, const float* __restrict__ b1_iu,
    const float* __restrict__ W2_iu, const float* __restrict__ b2_iu,
    float* __restrict__ out)
{
    __shared__ __align__(16) _Float16 wlds[49152];   // 96 KiB: W0 (64) + W1 (32) frags

    const int dec = blockIdx.x & 1;
    const void* src_tab = dec ? tabI : tabU;
    const void* dst_tab = dec ? tabU : tabI;
    const int* src_idx = dec ? iu_src : ui_src;
    const int* dst_idx = dec ? iu_dst : ui_dst;
    const float* W0 = dec ? W0_iu : W0_ui;
    const float* b0 = dec ? b0_iu : b0_ui;
    const float* W1 = dec ? W1_iu : W1_ui;
    const float* b1 = dec ? b1_iu : b1_ui;
    const float* W2 = dec ? W2_iu : W2_ui;
    const float* b2 = dec ? b2_iu : b2_ui;
    float* op = out + (dec ? E_EDGES : 0);

    const int tid = threadIdx.x;
    const int l = tid & 63;        // lane
    const int w = tid >> 6;        // wave 0..7
    const int n = l & 15;
    const int g = l >> 4;          // lane quad 0..3

    // ---- preload W0^T A-frags: frag f = kk*8 + hr, 64 frags, 8 waves x 8 ----
    // frag elem (lane l, i): W0[(kk*32 + g*8 + i)*128 + hr*16 + n]
    #pragma unroll
    for (int q = 0; q < 8; ++q) {
        const int f = w * 8 + q;
        const int kk = f >> 3, hr = f & 7;
        const int kbase = kk * 32 + g * 8;
        const int col = hr * 16 + n;
        half8 fr;
        #pragma unroll
        for (int i = 0; i < 8; ++i) fr[i] = (_Float16)W0[(kbase + i) * 128 + col];
        *(half8*)&wlds[f * 512 + l * 8] = fr;
    }
    // ---- preload W1^T A-frags: 32 frags, 8 waves x 4 ----
    #pragma unroll
    for (int q = 0; q < 4; ++q) {
        const int f = w * 4 + q;
        const int kk = f >> 3, hr = f & 7;
        const int kbase = kk * 32 + g * 8;
        const int col = hr * 16 + n;
        half8 fr;
        #pragma unroll
        for (int i = 0; i < 8; ++i) fr[i] = (_Float16)W1[(kbase + i) * 128 + col];
        *(half8*)&wlds[32768 + f * 512 + l * 8] = fr;
    }

    // ---- loop-invariant per-lane epilogue constants (C row = hr*16 + g*4 + v)
    f32x4 b0r[8], b1r[8], w2r[8];
    #pragma unroll
    for (int hr = 0; hr < 8; ++hr) {
        b0r[hr] = *(const f32x4*)&b0[hr * 16 + g * 4];
        b1r[hr] = *(const f32x4*)&b1[hr * 16 + g * 4];
        w2r[hr] = *(const f32x4*)&W2[hr * 16 + g * 4];
    }
    const float b2s = b2[0];
    __syncthreads();   // only barrier; main loop is barrier-free

    const half8* w0f = (const half8*)&wlds[0];
    const half8* w1f = (const half8*)&wlds[32768];

    const int wid = (blockIdx.x >> 1) * 8 + w;     // 0..2047 within decoder

    for (int t = wid; t < NTILES; t += WAVES_PER_DEC) {
        const int e0 = t * 32;

        // ---- gather X^T B-frags: 2 sets x 16 edges, K=256 (src||dst) ----
        half8 a[2][8];
        #pragma unroll
        for (int s = 0; s < 2; ++s) {
            const int e = e0 + s * 16 + n;          // B col = lane n
            const int si = src_idx[e];
            const int di = dst_idx[e];
            if constexpr (PRE16) {
                const half8* rs = (const half8*)((const _Float16*)src_tab + (size_t)si * 128) + g;
                const half8* rd = (const half8*)((const _Float16*)dst_tab + (size_t)di * 128) + g;
                #pragma unroll
                for (int kk = 0; kk < 4; ++kk) a[s][kk]     = rs[kk * 4];
                #pragma unroll
                for (int kk = 0; kk < 4; ++kk) a[s][4 + kk] = rd[kk * 4];
            } else {
                const float* rs = (const float*)src_tab + (size_t)si * 128 + g * 8;
                const float* rd = (const float*)dst_tab + (size_t)di * 128 + g * 8;
                #pragma unroll
                for (int kk = 0; kk < 8; ++kk) {
                    const float* base = (kk < 4) ? (rs + kk * 32) : (rd + (kk - 4) * 32);
                    float4 p0 = *(const float4*)base;
                    float4 p1 = *(const float4*)(base + 4);
                    half8 fr;
                    fr[0] = (_Float16)p0.x; fr[1] = (_Float16)p0.y;
                    fr[2] = (_Float16)p0.z; fr[3] = (_Float16)p0.w;
                    fr[4] = (_Float16)p1.x; fr[5] = (_Float16)p1.y;
                    fr[6] = (_Float16)p1.z; fr[7] = (_Float16)p1.w;
                    a[s][kk] = fr;
                }
            }
        }

        // ---- layer 0: acc0[s][hr] = W0^T @ X^T (accs in AGPRs) ----
        f32x4 acc0[2][8];
        #pragma unroll
        for (int s = 0; s < 2; ++s)
            #pragma unroll
            for (int hr = 0; hr < 8; ++hr) acc0[s][hr] = (f32x4){0.f, 0.f, 0.f, 0.f};
        #pragma unroll
        for (int kk = 0; kk < 8; ++kk) {
            #pragma unroll
            for (int hr = 0; hr < 8; ++hr) {
                const half8 wf = w0f[(kk * 8 + hr) * 64 + l];
                mfma_a(acc0[0][hr], wf, a[0][kk]);
                mfma_a(acc0[1][hr], wf, a[1][kk]);
            }
        }

        // ---- bias+ELU + pack + permlane: C-layout -> layer-1 B-frags ----
        unsigned int v01[2][8], v23[2][8];
        #pragma unroll
        for (int hr = 0; hr < 8; ++hr) {
            #pragma unroll
            for (int s = 0; s < 2; ++s) {
                half2v p01, p23;
                p01[0] = (_Float16)elu_f(acc0[s][hr][0] + b0r[hr][0]);
                p01[1] = (_Float16)elu_f(acc0[s][hr][1] + b0r[hr][1]);
                p23[0] = (_Float16)elu_f(acc0[s][hr][2] + b0r[hr][2]);
                p23[1] = (_Float16)elu_f(acc0[s][hr][3] + b0r[hr][3]);
                v01[s][hr] = __builtin_bit_cast(unsigned int, p01);
                v23[s][hr] = __builtin_bit_cast(unsigned int, p23);
            }
        }
        half8 bfr[2][4];
        #pragma unroll
        for (int s = 0; s < 2; ++s) {
            #pragma unroll
            for (int kk = 0; kk < 4; ++kk) {
                unsigned int w0lo, w0hi, w1lo, w1hi;
                xpose_pair(v01[s][2 * kk], v01[s][2 * kk + 1], w0lo, w0hi);
                xpose_pair(v23[s][2 * kk], v23[s][2 * kk + 1], w1lo, w1hi);
                uint4v wd;
                wd.x = w0lo;   // elems i0,i1 (v=0,1 from groups {0,2})
                wd.y = w1lo;   // elems i2,i3 (v=2,3 from groups {0,2})
                wd.z = w0hi;   // elems i4,i5 (v=0,1 from groups {1,3})
                wd.w = w1hi;   // elems i6,i7 (v=2,3 from groups {1,3})
                bfr[s][kk] = __builtin_bit_cast(half8, wd);
            }
        }

        // ---- layer 1: acc1[s][hr] = W1^T @ H0^T (accs in AGPRs) ----
        f32x4 acc1[2][8];
        #pragma unroll
        for (int s = 0; s < 2; ++s)
            #pragma unroll
            for (int hr = 0; hr < 8; ++hr) acc1[s][hr] = (f32x4){0.f, 0.f, 0.f, 0.f};
        #pragma unroll
        for (int kk = 0; kk < 4; ++kk) {
            #pragma unroll
            for (int hr = 0; hr < 8; ++hr) {
                const half8 wf = w1f[(kk * 8 + hr) * 64 + l];
                mfma_a(acc1[0][hr], wf, bfr[0][kk]);
                mfma_a(acc1[1][hr], wf, bfr[1][kk]);
            }
        }

        // ---- layer 2: per-lane 32-ch dot, reduce across lane quads ----
        float accs0 = 0.f, accs1 = 0.f;
        #pragma unroll
        for (int hr = 0; hr < 8; ++hr) {
            #pragma unroll
            for (int v = 0; v < 4; ++v) {
                accs0 += elu_f(acc1[0][hr][v] + b1r[hr][v]) * w2r[hr][v];
                accs1 += elu_f(acc1[1][hr][v] + b1r[hr][v]) * w2r[hr][v];
            }
        }
        accs0 += __shfl_xor(accs0, 16); accs0 += __shfl_xor(accs0, 32);
        accs1 += __shfl_xor(accs1, 16); accs1 += __shfl_xor(accs1, 32);
        // lane l (<32) -> edge e0 + l; set = bit4 of l
        if (l < 32) {
            const float sel = (l & 16) ? accs1 : accs0;
            op[e0 + l] = 1.f / (1.f + __expf(-(sel + b2s)));
        }
    }
}

extern "C" void kernel_launch(void* const* d_in, const int* in_sizes, int n_in,
                              void* d_out, int out_size, void* d_ws, size_t ws_size,
                              hipStream_t stream) {
    const float* user_emb = (const float*)d_in[0];
    const float* item_emb = (const float*)d_in[1];
    const int* ui_src = (const int*)d_in[2];
    const int* ui_dst = (const int*)d_in[3];
    const int* iu_src = (const int*)d_in[4];
    const int* iu_dst = (const int*)d_in[5];
    const float* W0_ui = (const float*)d_in[6];
    const float* b0_ui = (const float*)d_in[7];
    const float* W1_ui = (const float*)d_in[8];
    const float* b1_ui = (const float*)d_in[9];
    const float* W2_ui = (const float*)d_in[10];
    const float* b2_ui = (const float*)d_in[11];
    const float* W0_iu = (const float*)d_in[12];
    const float* b0_iu = (const float*)d_in[13];
    const float* W1_iu = (const float*)d_in[14];
    const float* b1_iu = (const float*)d_in[15];
    const float* W2_iu = (const float*)d_in[16];
    const float* b2_iu = (const float*)d_in[17];
    float* out = (float*)d_out;

    const size_t nuser = (size_t)100000 * 128;
    const size_t nitem = (size_t)50000 * 128;
    const size_t need = (nuser + nitem) * sizeof(unsigned short);

    if (ws_size >= need) {
        _Float16* u16 = (_Float16*)d_ws;
        _Float16* i16 = u16 + nuser;
        const int n4u = (int)(nuser / 4);
        const int n4i = (int)(nitem / 4);
        cvt_tables<<<dim3((unsigned)((n4u + n4i + 255) / 256)), dim3(256), 0, stream>>>(
            user_emb, item_emb, u16, i16, n4u, n4i);
        edge_mlp<true><<<dim3(GRID_BLKS), dim3(512), 0, stream>>>(
            (const void*)u16, (const void*)i16,
            ui_src, ui_dst, iu_src, iu_dst,
            W0_ui, b0_ui, W1_ui, b1_ui, W2_ui, b2_ui,
            W0_iu, b0_iu, W1_iu, b1_iu, W2_iu, b2_iu, out);
    } else {
        edge_mlp<false><<<dim3(GRID_BLKS), dim3(512), 0, stream>>>(
            (const void*)user_emb, (const void*)item_emb,
            ui_src, ui_dst, iu_src, iu_dst,
            W0_ui, b0_ui, W1_ui, b1_ui, W2_ui, b2_ui,
            W0_iu, b0_iu, W1_iu, b1_iu, W2_iu, b2_iu, out);
    }
}

// Round 7
// 380.358 us; speedup vs baseline: 5.5633x; 1.1114x over previous
//
#include <hip/hip_runtime.h>
#include <cstdint>
#include <cstddef>

// ---------------------------------------------------------------------------
// EdgeDecoder, swapped-operand formulation, AGPR accumulators + pipelined gather.
//   Layer0: D0 = W0^T (A-frag, LDS) @ X^T (B-frag, gathered)   [C: lane=edge col]
//   transform: ELU + cvt_pkrtz + permlane32/16_swap -> layer-1 B-frags (no LDS)
//   Layer1: D1 = W1^T (A-frag, LDS) @ H0^T (B-frag, registers)
//   Layer2: per-lane dot (32 ch) + xor16/xor32 reduce + coalesced store
// Round-5 fixed the spill (AGPR-pinned accs via inline-asm "+a"): 320 us,
// WRITE 12 MB, FETCH 470 MB, VALUBusy 53%, MfmaUtil 27% -- latency-gap bound.
// Round-6/7 changes:
//   * software-pipelined gather: idx loads 1 tile ahead; embedding gathers for
//     tile t+1 issued right after layer-0 consumes a[] (same regs, zero extra
//     VGPR), hidden under transform+layer1+epilogue. sched_barrier(0) pins the
//     loads below the MFMAs so regalloc can't rename-and-hoist (spill guard).
//   * bias folded into AGPR C-init (acc = b0r/b1r): -128 VALU adds/tile.
//   * cvt_pkrtz packed f32->f16 in transform (r7: fix builtin return type --
//     __fp16 vector, bit_cast straight to u32).
// ---------------------------------------------------------------------------

#define E_EDGES       1000000
#define NTILES        31250      // E / 32
#define GRID_BLKS     512        // 256 blocks per decoder, interleaved
#define WAVES_PER_DEC 2048       // 256 blocks * 8 waves

typedef _Float16 half8  __attribute__((ext_vector_type(8)));
typedef _Float16 half4v __attribute__((ext_vector_type(4)));
typedef float    f32x4  __attribute__((ext_vector_type(4)));
typedef unsigned int uint4v __attribute__((ext_vector_type(4)));

__device__ __forceinline__ float elu_f(float x) {
    return (x > 0.f) ? x : (__expf(x) - 1.f);
}

// packed f32x2 -> f16x2 (RTZ), as a raw 32-bit word
__device__ __forceinline__ unsigned int pk16(float lo, float hi) {
    return __builtin_bit_cast(unsigned int, __builtin_amdgcn_cvt_pkrtz(lo, hi));
}

// MFMA with accumulator pinned to AGPRs ("a" register class). D=A*B+C, C==D.
__device__ __forceinline__ void mfma_a(f32x4& acc, half8 af, half8 bf) {
    asm("v_mfma_f32_16x16x32_f16 %0, %1, %2, %0"
        : "+a"(acc)
        : "v"(af), "v"(bf));
}

// Cross-lane word redistribution for C-layout -> B-fragment conversion.
//   lo[l] = (l<32 ? A0 : A1)[ ((l>>4)&1)*32 +      (l&15) ]
//   hi[l] = (l<32 ? A0 : A1)[ ((l>>4)&1)*32 + 16 + (l&15) ]
// permlane32_swap + permlane16_swap (both outputs used). Verified rounds 1-5.
__device__ __forceinline__ void xpose_pair(unsigned int A0, unsigned int A1,
                                           unsigned int& lo, unsigned int& hi) {
#if __has_builtin(__builtin_amdgcn_permlane32_swap) && __has_builtin(__builtin_amdgcn_permlane16_swap)
    auto t = __builtin_amdgcn_permlane32_swap(A0, A1, false, false);
    auto u = __builtin_amdgcn_permlane16_swap(t[0], t[1], false, false);
    lo = u[0]; hi = u[1];
#else
    const int l = (int)(threadIdx.x & 63);
    const int src = (((l >> 4) & 1) << 5) | (l & 15);
    unsigned int x0 = (unsigned int)__shfl((int)A0, src);
    unsigned int x1 = (unsigned int)__shfl((int)A1, src);
    unsigned int y0 = (unsigned int)__shfl((int)A0, src + 16);
    unsigned int y1 = (unsigned int)__shfl((int)A1, src + 16);
    lo = (l < 32) ? x0 : x1;
    hi = (l < 32) ? y0 : y1;
#endif
}

// fused f32 -> f16 conversion of both embedding tables
__global__ void cvt_tables(const float* __restrict__ u, const float* __restrict__ it,
                           _Float16* __restrict__ ou, _Float16* __restrict__ oi,
                           int n4u, int n4i) {
    int i = blockIdx.x * blockDim.x + threadIdx.x;
    const float4* src; half4v* dst; int j;
    if (i < n4u) { src = (const float4*)u; dst = (half4v*)ou; j = i; }
    else {
        j = i - n4u;
        if (j >= n4i) return;
        src = (const float4*)it; dst = (half4v*)oi;
    }
    float4 f = src[j];
    half4v h;
    h[0] = (_Float16)f.x; h[1] = (_Float16)f.y;
    h[2] = (_Float16)f.z; h[3] = (_Float16)f.w;
    dst[j] = h;
}

template<bool PRE16>
__device__ __forceinline__ void gather_tiles(
    half8 (&a)[2][8], const void* src_tab, const void* dst_tab,
    const int (&si)[2], const int (&di)[2], int g)
{
    #pragma unroll
    for (int s = 0; s < 2; ++s) {
        if constexpr (PRE16) {
            const half8* rs = (const half8*)((const _Float16*)src_tab + (size_t)si[s] * 128) + g;
            const half8* rd = (const half8*)((const _Float16*)dst_tab + (size_t)di[s] * 128) + g;
            #pragma unroll
            for (int kk = 0; kk < 4; ++kk) a[s][kk]     = rs[kk * 4];
            #pragma unroll
            for (int kk = 0; kk < 4; ++kk) a[s][4 + kk] = rd[kk * 4];
        } else {
            const float* rs = (const float*)src_tab + (size_t)si[s] * 128 + g * 8;
            const float* rd = (const float*)dst_tab + (size_t)di[s] * 128 + g * 8;
            #pragma unroll
            for (int kk = 0; kk < 8; ++kk) {
                const float* base = (kk < 4) ? (rs + kk * 32) : (rd + (kk - 4) * 32);
                float4 p0 = *(const float4*)base;
                float4 p1 = *(const float4*)(base + 4);
                half8 fr;
                fr[0] = (_Float16)p0.x; fr[1] = (_Float16)p0.y;
                fr[2] = (_Float16)p0.z; fr[3] = (_Float16)p0.w;
                fr[4] = (_Float16)p1.x; fr[5] = (_Float16)p1.y;
                fr[6] = (_Float16)p1.z; fr[7] = (_Float16)p1.w;
                a[s][kk] = fr;
            }
        }
    }
}

__device__ __forceinline__ void idx_load(const int* __restrict__ src_idx,
                                         const int* __restrict__ dst_idx,
                                         int t, int n, int (&si)[2], int (&di)[2])
{
    #pragma unroll
    for (int s = 0; s < 2; ++s) {
        const int e = t * 32 + s * 16 + n;
        si[s] = src_idx[e];
        di[s] = dst_idx[e];
    }
}

template<bool PRE16>
__global__ __launch_bounds__(512, 2) void edge_mlp(
    const void* __restrict__ tabU, const void* __restrict__ tabI,
    const int* __restrict__ ui_src, const int* __restrict__ ui_dst,
    const int* __restrict__ iu_src, const int* __restrict__ iu_dst,
    const float* __restrict__ W0_ui, const float* __restrict__ b0_ui,
    const float* __restrict__ W1_ui, const float* __restrict__ b1_ui,
    const float* __restrict__ W2_ui, const float* __restrict__ b2_ui,
    const float* __restrict__ W0_iu, const float* __restrict__ b0_iu,
    const float* __restrict__ W1_iu, const float* __restrict__ b1_iu,
    const float* __restrict__ W2_iu, const float* __restrict__ b2_iu,
    float* __restrict__ out)
{
    __shared__ __align__(16) _Float16 wlds[49152];   // 96 KiB: W0 (64) + W1 (32) frags

    const int dec = blockIdx.x & 1;
    const void* src_tab = dec ? tabI : tabU;
    const void* dst_tab = dec ? tabU : tabI;
    const int* src_idx = dec ? iu_src : ui_src;
    const int* dst_idx = dec ? iu_dst : ui_dst;
    const float* W0 = dec ? W0_iu : W0_ui;
    const float* b0 = dec ? b0_iu : b0_ui;
    const float* W1 = dec ? W1_iu : W1_ui;
    const float* b1 = dec ? b1_iu : b1_ui;
    const float* W2 = dec ? W2_iu : W2_ui;
    const float* b2 = dec ? b2_iu : b2_ui;
    float* op = out + (dec ? E_EDGES : 0);

    const int tid = threadIdx.x;
    const int l = tid & 63;        // lane
    const int w = tid >> 6;        // wave 0..7
    const int n = l & 15;
    const int g = l >> 4;          // lane quad 0..3

    // ---- preload W0^T A-frags: frag f = kk*8 + hr, 64 frags, 8 waves x 8 ----
    // frag elem (lane l, i): W0[(kk*32 + g*8 + i)*128 + hr*16 + n]
    #pragma unroll
    for (int q = 0; q < 8; ++q) {
        const int f = w * 8 + q;
        const int kk = f >> 3, hr = f & 7;
        const int kbase = kk * 32 + g * 8;
        const int col = hr * 16 + n;
        half8 fr;
        #pragma unroll
        for (int i = 0; i < 8; ++i) fr[i] = (_Float16)W0[(kbase + i) * 128 + col];
        *(half8*)&wlds[f * 512 + l * 8] = fr;
    }
    // ---- preload W1^T A-frags: 32 frags, 8 waves x 4 ----
    #pragma unroll
    for (int q = 0; q < 4; ++q) {
        const int f = w * 4 + q;
        const int kk = f >> 3, hr = f & 7;
        const int kbase = kk * 32 + g * 8;
        const int col = hr * 16 + n;
        half8 fr;
        #pragma unroll
        for (int i = 0; i < 8; ++i) fr[i] = (_Float16)W1[(kbase + i) * 128 + col];
        *(half8*)&wlds[32768 + f * 512 + l * 8] = fr;
    }

    // ---- loop-invariant per-lane epilogue constants (C row = hr*16 + g*4 + v)
    f32x4 b0r[8], b1r[8], w2r[8];
    #pragma unroll
    for (int hr = 0; hr < 8; ++hr) {
        b0r[hr] = *(const f32x4*)&b0[hr * 16 + g * 4];
        b1r[hr] = *(const f32x4*)&b1[hr * 16 + g * 4];
        w2r[hr] = *(const f32x4*)&W2[hr * 16 + g * 4];
    }
    const float b2s = b2[0];
    __syncthreads();   // only barrier; main loop is barrier-free

    const half8* w0f = (const half8*)&wlds[0];
    const half8* w1f = (const half8*)&wlds[32768];

    const int wid = (blockIdx.x >> 1) * 8 + w;     // 0..2047 within decoder

    // ================= software-pipelined main loop =================
    int tc = wid;                                  // current tile (always valid)
    int si[2], di[2];
    idx_load(src_idx, dst_idx, tc, n, si, di);
    half8 a[2][8];
    gather_tiles<PRE16>(a, src_tab, dst_tab, si, di, g);
    int tn = tc + WAVES_PER_DEC;                   // next tile (maybe invalid)
    idx_load(src_idx, dst_idx, (tn < NTILES) ? tn : tc, n, si, di);

    while (true) {
        // ---- layer 0: acc0[s][hr] = W0^T @ X^T, bias in C-init (AGPRs) ----
        f32x4 acc0[2][8];
        #pragma unroll
        for (int s = 0; s < 2; ++s)
            #pragma unroll
            for (int hr = 0; hr < 8; ++hr) acc0[s][hr] = b0r[hr];
        #pragma unroll
        for (int kk = 0; kk < 8; ++kk) {
            #pragma unroll
            for (int hr = 0; hr < 8; ++hr) {
                const half8 wf = w0f[(kk * 8 + hr) * 64 + l];
                mfma_a(acc0[0][hr], wf, a[0][kk]);
                mfma_a(acc0[1][hr], wf, a[1][kk]);
            }
        }

        // pin the prefetch below the MFMAs (a[] regs now dead -> reuse, no spill)
        __builtin_amdgcn_sched_barrier(0);

        // ---- prefetch next tile's gathers into a[] (latency hidden below) ----
        gather_tiles<PRE16>(a, src_tab, dst_tab, si, di, g);
        // ---- prefetch idx for the tile after next ----
        {
            const int tnc = (tn < NTILES) ? tn : tc;
            const int t2 = tn + WAVES_PER_DEC;
            const int t2c = (t2 < NTILES) ? t2 : tnc;
            idx_load(src_idx, dst_idx, t2c, n, si, di);
        }

        // ---- ELU + cvt_pkrtz + permlane: C-layout -> layer-1 B-frags ----
        unsigned int v01[2][8], v23[2][8];
        #pragma unroll
        for (int hr = 0; hr < 8; ++hr) {
            #pragma unroll
            for (int s = 0; s < 2; ++s) {
                v01[s][hr] = pk16(elu_f(acc0[s][hr][0]), elu_f(acc0[s][hr][1]));
                v23[s][hr] = pk16(elu_f(acc0[s][hr][2]), elu_f(acc0[s][hr][3]));
            }
        }
        half8 bfr[2][4];
        #pragma unroll
        for (int s = 0; s < 2; ++s) {
            #pragma unroll
            for (int kk = 0; kk < 4; ++kk) {
                unsigned int w0lo, w0hi, w1lo, w1hi;
                xpose_pair(v01[s][2 * kk], v01[s][2 * kk + 1], w0lo, w0hi);
                xpose_pair(v23[s][2 * kk], v23[s][2 * kk + 1], w1lo, w1hi);
                uint4v wd;
                wd.x = w0lo;   // elems i0,i1 (v=0,1 from groups {0,2})
                wd.y = w1lo;   // elems i2,i3 (v=2,3 from groups {0,2})
                wd.z = w0hi;   // elems i4,i5 (v=0,1 from groups {1,3})
                wd.w = w1hi;   // elems i6,i7 (v=2,3 from groups {1,3})
                bfr[s][kk] = __builtin_bit_cast(half8, wd);
            }
        }

        // ---- layer 1: acc1[s][hr] = W1^T @ H0^T, bias in C-init (AGPRs) ----
        f32x4 acc1[2][8];
        #pragma unroll
        for (int s = 0; s < 2; ++s)
            #pragma unroll
            for (int hr = 0; hr < 8; ++hr) acc1[s][hr] = b1r[hr];
        #pragma unroll
        for (int kk = 0; kk < 4; ++kk) {
            #pragma unroll
            for (int hr = 0; hr < 8; ++hr) {
                const half8 wf = w1f[(kk * 8 + hr) * 64 + l];
                mfma_a(acc1[0][hr], wf, bfr[0][kk]);
                mfma_a(acc1[1][hr], wf, bfr[1][kk]);
            }
        }

        // ---- layer 2: per-lane 32-ch dot, reduce across lane quads ----
        float accs0 = 0.f, accs1 = 0.f;
        #pragma unroll
        for (int hr = 0; hr < 8; ++hr) {
            #pragma unroll
            for (int v = 0; v < 4; ++v) {
                accs0 += elu_f(acc1[0][hr][v]) * w2r[hr][v];
                accs1 += elu_f(acc1[1][hr][v]) * w2r[hr][v];
            }
        }
        accs0 += __shfl_xor(accs0, 16); accs0 += __shfl_xor(accs0, 32);
        accs1 += __shfl_xor(accs1, 16); accs1 += __shfl_xor(accs1, 32);
        // lane l (<32) -> edge e0 + l; set = bit4 of l
        if (l < 32) {
            const float sel = (l & 16) ? accs1 : accs0;
            op[tc * 32 + l] = 1.f / (1.f + __expf(-(sel + b2s)));
        }

        if (tn >= NTILES) break;
        tc = tn;
        tn = tc + WAVES_PER_DEC;
    }
}

extern "C" void kernel_launch(void* const* d_in, const int* in_sizes, int n_in,
                              void* d_out, int out_size, void* d_ws, size_t ws_size,
                              hipStream_t stream) {
    const float* user_emb = (const float*)d_in[0];
    const float* item_emb = (const float*)d_in[1];
    const int* ui_src = (const int*)d_in[2];
    const int* ui_dst = (const int*)d_in[3];
    const int* iu_src = (const int*)d_in[4];
    const int* iu_dst = (const int*)d_in[5];
    const float* W0_ui = (const float*)d_in[6];
    const float* b0_ui = (const float*)d_in[7];
    const float* W1_ui = (const float*)d_in[8];
    const float* b1_ui = (const float*)d_in[9];
    const float* W2_ui = (const float*)d_in[10];
    const float* b2_ui = (const float*)d_in[11];
    const float* W0_iu = (const float*)d_in[12];
    const float* b0_iu = (const float*)d_in[13];
    const float* W1_iu = (const float*)d_in[14];
    const float* b1_iu = (const float*)d_in[15];
    const float* W2_iu = (const float*)d_in[16];
    const float* b2_iu = (const float*)d_in[17];
    float* out = (float*)d_out;

    const size_t nuser = (size_t)100000 * 128;
    const size_t nitem = (size_t)50000 * 128;
    const size_t need = (nuser + nitem) * sizeof(unsigned short);

    if (ws_size >= need) {
        _Float16* u16 = (_Float16*)d_ws;
        _Float16* i16 = u16 + nuser;
        const int n4u = (int)(nuser / 4);
        const int n4i = (int)(nitem / 4);
        cvt_tables<<<dim3((unsigned)((n4u + n4i + 255) / 256)), dim3(256), 0, stream>>>(
            user_emb, item_emb, u16, i16, n4u, n4i);
        edge_mlp<true><<<dim3(GRID_BLKS), dim3(512), 0, stream>>>(
            (const void*)u16, (const void*)i16,
            ui_src, ui_dst, iu_src, iu_dst,
            W0_ui, b0_ui, W1_ui, b1_ui, W2_ui, b2_ui,
            W0_iu, b0_iu, W1_iu, b1_iu, W2_iu, b2_iu, out);
    } else {
        edge_mlp<false><<<dim3(GRID_BLKS), dim3(512), 0, stream>>>(
            (const void*)user_emb, (const void*)item_emb,
            ui_src, ui_dst, iu_src, iu_dst,
            W0_ui, b0_ui, W1_ui, b1_ui, W2_ui, b2_ui,
            W0_iu, b0_iu, W1_iu, b1_iu, W2_iu, b2_iu, out);
    }
}